// Round 6
// baseline (437.498 us; speedup 1.0000x reference)
//
#include <hip/hip_runtime.h>
#include <stdint.h>

#define SEQ   2048
#define BATCH 4
#define NH    16
#define HD    64
#define DIMN  1024
#define MROWS (BATCH*SEQ)   // 8192

typedef __attribute__((ext_vector_type(8))) short          bf16x8;
typedef __attribute__((ext_vector_type(8))) unsigned short ushort8;
typedef __attribute__((ext_vector_type(4))) float          f32x4;

static __device__ __forceinline__ unsigned short f2bf(float f) {
    unsigned int u = __builtin_bit_cast(unsigned int, f);
    u += 0x7fffu + ((u >> 16) & 1u);          // RNE
    return (unsigned short)(u >> 16);
}
// RNE-ish (round-half-up) pack: 3 ops
static __device__ __forceinline__ unsigned int pack2bf(float lo, float hi) {
    unsigned int a = __builtin_bit_cast(unsigned int, lo) + 0x8000u;
    unsigned int b = __builtin_bit_cast(unsigned int, hi) + 0x8000u;
    return __builtin_amdgcn_perm(b, a, 0x07060302u);
}
// truncating pack: 1 op (P in [0,1], rel err <= 2^-8, fine for softmax weights)
static __device__ __forceinline__ unsigned int pack2bf_trunc(float lo, float hi) {
    return __builtin_amdgcn_perm(__builtin_bit_cast(unsigned int, hi),
                                 __builtin_bit_cast(unsigned int, lo), 0x07060302u);
}

// ---------------------------------------------------------------- fused prologue
// blockIdx.x: [0,4096) x-cast; [4096,6144) 4 weight casts; [6144,6400) rope
// tables; 6400 mask->u64. All branches wave-uniform.
__global__ __launch_bounds__(256) void prologue_kernel(
        const float* __restrict__ x,
        const float* __restrict__ qw, const float* __restrict__ kw,
        const float* __restrict__ vw, const float* __restrict__ ow,
        unsigned short* __restrict__ xb,
        unsigned short* __restrict__ wq, unsigned short* __restrict__ wk,
        unsigned short* __restrict__ wv, unsigned short* __restrict__ wo,
        float* __restrict__ cosT, float* __restrict__ sinT,
        const unsigned char* __restrict__ mask, unsigned long long* __restrict__ m64) {
    const int bx = blockIdx.x, tid = threadIdx.x;
    if (bx < 4096 + 2048) {
        const float* s; unsigned short* d; int i;
        if (bx < 4096) { s = x; d = xb; i = bx * 2048 + tid * 8; }
        else {
            int wb = bx - 4096;
            int wsel = wb >> 9;
            s = wsel == 0 ? qw : (wsel == 1 ? kw : (wsel == 2 ? vw : ow));
            d = wsel == 0 ? wq : (wsel == 1 ? wk : (wsel == 2 ? wv : wo));
            i = (wb & 511) * 2048 + tid * 8;
        }
        float4 a = *(const float4*)(s + i);
        float4 b = *(const float4*)(s + i + 4);
        ushort8 o;
        o[0]=f2bf(a.x); o[1]=f2bf(a.y); o[2]=f2bf(a.z); o[3]=f2bf(a.w);
        o[4]=f2bf(b.x); o[5]=f2bf(b.y); o[6]=f2bf(b.z); o[7]=f2bf(b.w);
        *(ushort8*)(d + i) = o;
    } else if (bx < 6400) {
        int idx = (bx - 6144) * 256 + tid;        // SEQ*32
        int s = idx >> 5, j = idx & 31;
        float t = (float)(2 * j) / 64.0f;
        float freq = 1.0f / powf(10000.0f, t);
        float ang  = (float)s * freq;
        cosT[idx] = cosf(ang);
        sinT[idx] = sinf(ang);
    } else {
        if (tid < 128) {
            int b = tid >> 5, kt = tid & 31;
            const unsigned char* p = mask + b * SEQ + kt * 64;
            unsigned long long v = 0;
            for (int j = 0; j < 64; j++) v |= (unsigned long long)(p[j] != 0) << j;
            m64[tid] = v;
        }
    }
}

// ---------------------------------------------------------------- fused Q,K,V^T GEMM
// blockIdx.x: [0..7]=Q, [8..15]=K (both +RoPE, out [B,H,S,D]), [16..23]=V^T
// (out [B,H,D,S]). Q pre-scaled by 0.125*log2e for exp2-domain softmax.
__global__ __launch_bounds__(256) void gemm_qkvt(const unsigned short* __restrict__ X,
        const unsigned short* __restrict__ Wq, const unsigned short* __restrict__ Wk,
        const unsigned short* __restrict__ Wv,
        const float* __restrict__ bq, const float* __restrict__ bk, const float* __restrict__ bv,
        unsigned short* __restrict__ Qo, unsigned short* __restrict__ Ko, unsigned short* __restrict__ Vto,
        const float* __restrict__ cosT, const float* __restrict__ sinT) {
    __shared__ __align__(16) unsigned short As[128 * 32];
    __shared__ __align__(16) unsigned short Bs[128 * 32];
    const int which = blockIdx.x >> 3;
    const int tid  = threadIdx.x;
    const int wid  = tid >> 6, lane = tid & 63;
    const int quad = lane >> 4, l15 = lane & 15;
    const int wm   = wid >> 1,  wn  = wid & 1;

    const unsigned short *Ag, *Bg;
    int m0, n0;
    if (which < 2) {
        m0 = blockIdx.y * 128;                 // token rows
        n0 = (blockIdx.x & 7) * 128;           // embed cols
        Ag = X;  Bg = which == 0 ? Wq : Wk;
    } else {
        m0 = (blockIdx.x & 7) * 128;           // e rows
        n0 = blockIdx.y * 128;                 // token rows
        Ag = Wv; Bg = X;
    }

    f32x4 acc[4][4];
#pragma unroll
    for (int i = 0; i < 4; i++)
#pragma unroll
        for (int j = 0; j < 4; j++) acc[i][j] = (f32x4)0.0f;

    const int rb = wid * 32 + (lane >> 2);
    const int cb = (lane & 3) * 8;

    for (int k0 = 0; k0 < DIMN; k0 += 32) {
#pragma unroll
        for (int i = 0; i < 2; i++) {
            const unsigned short* ga = Ag + (size_t)(m0 + rb + i * 16) * DIMN + k0 + cb;
            __builtin_amdgcn_global_load_lds((const __attribute__((address_space(1))) void*)ga,
                (__attribute__((address_space(3))) void*)&As[(wid * 32 + i * 16) * 32], 16, 0, 0);
            const unsigned short* gb = Bg + (size_t)(n0 + rb + i * 16) * DIMN + k0 + cb;
            __builtin_amdgcn_global_load_lds((const __attribute__((address_space(1))) void*)gb,
                (__attribute__((address_space(3))) void*)&Bs[(wid * 32 + i * 16) * 32], 16, 0, 0);
        }
        __syncthreads();
        bf16x8 af[4], bfr[4];
#pragma unroll
        for (int f = 0; f < 4; f++) af[f]  = *(const bf16x8*)&As[(wm * 64 + f * 16 + l15) * 32 + quad * 8];
#pragma unroll
        for (int f = 0; f < 4; f++) bfr[f] = *(const bf16x8*)&Bs[(wn * 64 + f * 16 + l15) * 32 + quad * 8];
#pragma unroll
        for (int fm = 0; fm < 4; fm++)
#pragma unroll
            for (int fn = 0; fn < 4; fn++)
                acc[fm][fn] = __builtin_amdgcn_mfma_f32_16x16x32_bf16(af[fm], bfr[fn], acc[fm][fn], 0, 0, 0);
        __syncthreads();
    }

    if (which < 2) {                            // Q or K: +bias, scale, RoPE, [B,H,S,D]
        const float* bias   = which == 0 ? bq : bk;
        unsigned short* Out = which == 0 ? Qo : Ko;
        const float scale = which == 0 ? 0.18033688011112042f : 1.0f;  // 0.125*log2e
        float bv4[4];
#pragma unroll
        for (int fn = 0; fn < 4; fn++) bv4[fn] = bias[n0 + wn * 64 + fn * 16 + l15];
        const int h = (n0 >> 6) + wn;
#pragma unroll
        for (int fm = 0; fm < 4; fm++)
#pragma unroll
            for (int r = 0; r < 4; r++) {
                int mrow = m0 + wm * 64 + fm * 16 + quad * 4 + r;
                int b = mrow >> 11, s = mrow & (SEQ - 1);
                unsigned short* orow = Out + ((size_t)(b * NH + h) * SEQ + s) * HD;
                float v0 = (acc[fm][0][r] + bv4[0]) * scale;
                float v1 = (acc[fm][1][r] + bv4[1]) * scale;
                float v2 = (acc[fm][2][r] + bv4[2]) * scale;
                float v3 = (acc[fm][3][r] + bv4[3]) * scale;
                int d0 = l15, d1 = 16 + l15;
                float c0 = cosT[s * 32 + d0], s0 = sinT[s * 32 + d0];
                float c1 = cosT[s * 32 + d1], s1 = sinT[s * 32 + d1];
                orow[d0]      = f2bf(v0 * c0 - v2 * s0);
                orow[d0 + 32] = f2bf(v0 * s0 + v2 * c0);
                orow[d1]      = f2bf(v1 * c1 - v3 * s1);
                orow[d1 + 32] = f2bf(v1 * s1 + v3 * c1);
            }
    } else {                                    // V^T: [B,H,D,S]
        float4 bb[4];
#pragma unroll
        for (int fm = 0; fm < 4; fm++)
            bb[fm] = *(const float4*)&bv[m0 + wm * 64 + fm * 16 + quad * 4];
        const int b     = n0 >> 11;
        const int sbase = (n0 & (SEQ - 1)) + wn * 64 + l15;
#pragma unroll
        for (int fm = 0; fm < 4; fm++)
#pragma unroll
            for (int r = 0; r < 4; r++) {
                int e = m0 + wm * 64 + fm * 16 + quad * 4 + r;
                float bval = r == 0 ? bb[fm].x : (r == 1 ? bb[fm].y : (r == 2 ? bb[fm].z : bb[fm].w));
                unsigned short* row = Vto + ((size_t)(b * NH + (e >> 6)) * HD + (e & 63)) * SEQ + sbase;
#pragma unroll
                for (int fn = 0; fn < 4; fn++)
                    row[fn * 16] = f2bf(acc[fm][fn][r] + bval);
            }
    }
}

// ---------------------------------------------------------------- output-proj GEMM (fp32 out)
__global__ __launch_bounds__(256) void gemm_bt(const unsigned short* __restrict__ A,
                                               const unsigned short* __restrict__ W,
                                               const float* __restrict__ bias,
                                               float* __restrict__ out) {
    __shared__ __align__(16) unsigned short As[128 * 32];
    __shared__ __align__(16) unsigned short Bs[128 * 32];
    const int tid  = threadIdx.x;
    const int wid  = tid >> 6, lane = tid & 63;
    const int quad = lane >> 4, l15 = lane & 15;
    const int wm   = wid >> 1,  wn  = wid & 1;
    const int m0   = blockIdx.y * 128, n0 = blockIdx.x * 128;

    f32x4 acc[4][4];
#pragma unroll
    for (int i = 0; i < 4; i++)
#pragma unroll
        for (int j = 0; j < 4; j++) acc[i][j] = (f32x4)0.0f;

    const int rb = wid * 32 + (lane >> 2);
    const int cb = (lane & 3) * 8;

    for (int k0 = 0; k0 < DIMN; k0 += 32) {
#pragma unroll
        for (int i = 0; i < 2; i++) {
            const unsigned short* ga = A + (size_t)(m0 + rb + i * 16) * DIMN + k0 + cb;
            __builtin_amdgcn_global_load_lds((const __attribute__((address_space(1))) void*)ga,
                (__attribute__((address_space(3))) void*)&As[(wid * 32 + i * 16) * 32], 16, 0, 0);
            const unsigned short* gb = W + (size_t)(n0 + rb + i * 16) * DIMN + k0 + cb;
            __builtin_amdgcn_global_load_lds((const __attribute__((address_space(1))) void*)gb,
                (__attribute__((address_space(3))) void*)&Bs[(wid * 32 + i * 16) * 32], 16, 0, 0);
        }
        __syncthreads();
        bf16x8 af[4], bfr[4];
#pragma unroll
        for (int f = 0; f < 4; f++) af[f]  = *(const bf16x8*)&As[(wm * 64 + f * 16 + l15) * 32 + quad * 8];
#pragma unroll
        for (int f = 0; f < 4; f++) bfr[f] = *(const bf16x8*)&Bs[(wn * 64 + f * 16 + l15) * 32 + quad * 8];
#pragma unroll
        for (int fm = 0; fm < 4; fm++)
#pragma unroll
            for (int fn = 0; fn < 4; fn++)
                acc[fm][fn] = __builtin_amdgcn_mfma_f32_16x16x32_bf16(af[fm], bfr[fn], acc[fm][fn], 0, 0, 0);
        __syncthreads();
    }

    float bv4[4];
#pragma unroll
    for (int fn = 0; fn < 4; fn++) bv4[fn] = bias[n0 + wn * 64 + fn * 16 + l15];
#pragma unroll
    for (int fm = 0; fm < 4; fm++)
#pragma unroll
        for (int r = 0; r < 4; r++) {
            int mrow = m0 + wm * 64 + fm * 16 + quad * 4 + r;
            float* orow = out + (size_t)mrow * DIMN + n0 + wn * 64;
#pragma unroll
            for (int fn = 0; fn < 4; fn++) orow[fn * 16 + l15] = acc[fm][fn][r] + bv4[fn];
        }
}

// ---------------------------------------------------------------- flash attention v6
// grid (SEQ/128, B*NH), 4 waves x 32 q-rows. NO LDS staging of K/V and NO
// barriers: K ([B,H,S,D]) and V^T ([B,H,D,S]) fragments are loaded per-lane
// directly from global (b128, L1-served; 4 waves share the 16 KB tile).
// LDS holds only the wave-private P^T round-trip (10 KiB). No online max
// (exp2 domain, Q pre-scaled). Short VMEM live ranges -> no scratch spill.
__global__ __launch_bounds__(256, 4) void attn_kernel(const unsigned short* __restrict__ Q,
                                                      const unsigned short* __restrict__ K,
                                                      const unsigned short* __restrict__ Vt,
                                                      const unsigned long long* __restrict__ M64,
                                                      unsigned short* __restrict__ Ob) {
    __shared__ __align__(16) unsigned short Ps[4 * 32 * 40];   // 10240 B, wave-private quarters

    const int tid  = threadIdx.x;
    const int wid  = tid >> 6, lane = tid & 63;
    const int quad = lane >> 4, l15 = lane & 15;
    const int bh = blockIdx.y, b = bh >> 4, h = bh & 15;
    const int q0 = blockIdx.x * 128;

    // persistent Q fragments: q = q0 + wid*32 + n*16 + l15
    bf16x8 qf[2][2];
#pragma unroll
    for (int n = 0; n < 2; n++) {
        const int qs = q0 + wid * 32 + n * 16 + l15;
#pragma unroll
        for (int dk = 0; dk < 2; dk++)
            qf[n][dk] = __builtin_bit_cast(bf16x8,
                *(const uint4*)&Q[((size_t)bh * SEQ + qs) * HD + dk * 32 + quad * 8]);
    }

    f32x4 Oa[4][2];                      // O^T: [df][n]; lane: d=df*16+quad*4+r, q=n*16+l15
#pragma unroll
    for (int i = 0; i < 4; i++)
#pragma unroll
        for (int n = 0; n < 2; n++) Oa[i][n] = (f32x4)0.0f;
    float ls[2] = {0.0f, 0.0f};

    unsigned short* Pw = &Ps[wid * 32 * 40];
    // lane-fixed global bases
    const unsigned short* Kf0 = K + (size_t)bh * SEQ * HD + (size_t)l15 * HD + quad * 8;
    const unsigned short* Vf0 = Vt + ((size_t)bh * HD + l15) * SEQ + quad * 8;
    const unsigned long long* Mrow = M64 + b * (SEQ / 64);

    for (int kt = 0; kt < SEQ / 64; kt++) {
        const int k0 = kt * 64;
        unsigned long long mb = Mrow[kt];

#pragma unroll
        for (int h2 = 0; h2 < 2; h2++) {      // 32-kk half
            // K fragments for this half, direct from global (A-operand layout)
            bf16x8 kf[2][2];
#pragma unroll
            for (int f2 = 0; f2 < 2; f2++)
#pragma unroll
                for (int dk = 0; dk < 2; dk++)
                    kf[f2][dk] = *(const bf16x8*)&Kf0[(size_t)(k0 + (h2 * 2 + f2) * 16) * HD + dk * 32];
            // V fragments for this half (issued early; latency overlaps softmax)
            bf16x8 vf[4];
#pragma unroll
            for (int df = 0; df < 4; df++)
                vf[df] = *(const bf16x8*)&Vf0[(size_t)(df * 16) * SEQ + k0 + h2 * 32];

            f32x4 st[2][2];
#pragma unroll
            for (int f2 = 0; f2 < 2; f2++)
#pragma unroll
                for (int n = 0; n < 2; n++) {
                    st[f2][n] = __builtin_amdgcn_mfma_f32_16x16x32_bf16(kf[f2][0], qf[n][0], (f32x4)0.0f, 0, 0, 0);
                    st[f2][n] = __builtin_amdgcn_mfma_f32_16x16x32_bf16(kf[f2][1], qf[n][1], st[f2][n], 0, 0, 0);
                }

            unsigned int mh = (unsigned int)(mb >> (h2 * 32));
            if (mh) {                         // wave-uniform; rare
#pragma unroll
                for (int f2 = 0; f2 < 2; f2++)
#pragma unroll
                    for (int n = 0; n < 2; n++)
#pragma unroll
                        for (int r = 0; r < 4; r++) {
                            int kk = f2 * 16 + quad * 4 + r;
                            if ((mh >> kk) & 1u) st[f2][n][r] = -1e9f;
                        }
            }

            // exp2, sum, pack, wave-private P^T half round-trip (no barrier)
#pragma unroll
            for (int f2 = 0; f2 < 2; f2++)
#pragma unroll
                for (int n = 0; n < 2; n++) {
                    float p0 = exp2f(st[f2][n][0]);
                    float p1 = exp2f(st[f2][n][1]);
                    float p2 = exp2f(st[f2][n][2]);
                    float p3 = exp2f(st[f2][n][3]);
                    ls[n] += (p0 + p1) + (p2 + p3);
                    uint2 w;
                    w.x = pack2bf_trunc(p0, p1);
                    w.y = pack2bf_trunc(p2, p3);
                    *(uint2*)&Pw[(n * 16 + l15) * 40 + f2 * 16 + quad * 4] = w;
                }
            bf16x8 pf[2];
#pragma unroll
            for (int n = 0; n < 2; n++)
                pf[n] = *(const bf16x8*)&Pw[(n * 16 + l15) * 40 + quad * 8];
#pragma unroll
            for (int df = 0; df < 4; df++)
#pragma unroll
                for (int n = 0; n < 2; n++)
                    Oa[df][n] = __builtin_amdgcn_mfma_f32_16x16x32_bf16(vf[df], pf[n], Oa[df][n], 0, 0, 0);
        }
    }

    float linv[2];
#pragma unroll
    for (int n = 0; n < 2; n++) {
        float l = ls[n];
        l += __shfl_xor(l, 16);
        l += __shfl_xor(l, 32);
        linv[n] = 1.0f / l;
    }

#pragma unroll
    for (int n = 0; n < 2; n++) {
        int s = q0 + wid * 32 + n * 16 + l15;
        unsigned short* orow = Ob + ((size_t)b * SEQ + s) * DIMN + h * HD + quad * 4;
#pragma unroll
        for (int df = 0; df < 4; df++) {
            uint2 w;
            w.x = pack2bf(Oa[df][n][0] * linv[n], Oa[df][n][1] * linv[n]);
            w.y = pack2bf(Oa[df][n][2] * linv[n], Oa[df][n][3] * linv[n]);
            *(uint2*)&orow[df * 16] = w;
        }
    }
}

// ---------------------------------------------------------------- launch
extern "C" void kernel_launch(void* const* d_in, const int* in_sizes, int n_in,
                              void* d_out, int out_size, void* d_ws, size_t ws_size,
                              hipStream_t stream) {
    (void)in_sizes; (void)n_in; (void)out_size; (void)ws_size;
    const float* x  = (const float*)d_in[0];
    const unsigned char* mask = (const unsigned char*)d_in[1];
    const float* q_w = (const float*)d_in[2];
    const float* q_b = (const float*)d_in[3];
    const float* k_w = (const float*)d_in[4];
    const float* k_b = (const float*)d_in[5];
    const float* v_w = (const float*)d_in[6];
    const float* v_b = (const float*)d_in[7];
    const float* o_w = (const float*)d_in[8];
    const float* o_b = (const float*)d_in[9];
    float* out = (float*)d_out;

    char* w = (char*)d_ws;
    unsigned short* xb = (unsigned short*)w;                        // 16 MiB (reused as attn output)
    unsigned short* wq = (unsigned short*)(w + (16u << 20));        // 4 x 2 MiB
    unsigned short* wk = wq + (1u << 20);
    unsigned short* wv = wk + (1u << 20);
    unsigned short* wo = wv + (1u << 20);
    float* cosT = (float*)(w + (24u << 20));                        // 256 KiB
    float* sinT = cosT + SEQ * 32;
    unsigned long long* m64 = (unsigned long long*)(w + (24u << 20) + (1u << 19)); // 1 KiB
    unsigned short* Qb  = (unsigned short*)(w + (25u << 20));       // 3 x 16 MiB
    unsigned short* Kb  = Qb + (8u << 20);
    unsigned short* Vtb = Kb + (8u << 20);
    unsigned short* Ob  = xb;                                       // reuse x's slot

    prologue_kernel<<<dim3(6401), 256, 0, stream>>>(x, q_w, k_w, v_w, o_w,
                                                    xb, wq, wk, wv, wo,
                                                    cosT, sinT, mask, m64);

    gemm_qkvt<<<dim3(24, 64), 256, 0, stream>>>(xb, wq, wk, wv, q_b, k_b, v_b,
                                                Qb, Kb, Vtb, cosT, sinT);

    attn_kernel<<<dim3(SEQ / 128, BATCH * NH), 256, 0, stream>>>(Qb, Kb, Vtb, m64, Ob);

    gemm_bt<<<dim3(DIMN / 128, MROWS / 128), 256, 0, stream>>>(Ob, wo, o_b, out);
}

// Round 7
// 321.161 us; speedup vs baseline: 1.3622x; 1.3622x over previous
//
#include <hip/hip_runtime.h>
#include <stdint.h>

#define SEQ   2048
#define BATCH 4
#define NH    16
#define HD    64
#define DIMN  1024
#define MROWS (BATCH*SEQ)   // 8192

typedef __attribute__((ext_vector_type(8))) short          bf16x8;
typedef __attribute__((ext_vector_type(8))) unsigned short ushort8;
typedef __attribute__((ext_vector_type(4))) float          f32x4;

static __device__ __forceinline__ unsigned short f2bf(float f) {
    unsigned int u = __builtin_bit_cast(unsigned int, f);
    u += 0x7fffu + ((u >> 16) & 1u);          // RNE
    return (unsigned short)(u >> 16);
}
// RNE-ish (round-half-up) pack: 3 ops
static __device__ __forceinline__ unsigned int pack2bf(float lo, float hi) {
    unsigned int a = __builtin_bit_cast(unsigned int, lo) + 0x8000u;
    unsigned int b = __builtin_bit_cast(unsigned int, hi) + 0x8000u;
    return __builtin_amdgcn_perm(b, a, 0x07060302u);
}
// truncating pack: 1 op (P in [0,1], rel err <= 2^-8, fine for softmax weights)
static __device__ __forceinline__ unsigned int pack2bf_trunc(float lo, float hi) {
    return __builtin_amdgcn_perm(__builtin_bit_cast(unsigned int, hi),
                                 __builtin_bit_cast(unsigned int, lo), 0x07060302u);
}

// ---------------------------------------------------------------- fused prologue
// blockIdx.x: [0,4096) x-cast; [4096,6144) 4 weight casts; [6144,6400) rope
// tables; 6400 mask->u64. All branches wave-uniform.
__global__ __launch_bounds__(256) void prologue_kernel(
        const float* __restrict__ x,
        const float* __restrict__ qw, const float* __restrict__ kw,
        const float* __restrict__ vw, const float* __restrict__ ow,
        unsigned short* __restrict__ xb,
        unsigned short* __restrict__ wq, unsigned short* __restrict__ wk,
        unsigned short* __restrict__ wv, unsigned short* __restrict__ wo,
        float* __restrict__ cosT, float* __restrict__ sinT,
        const unsigned char* __restrict__ mask, unsigned long long* __restrict__ m64) {
    const int bx = blockIdx.x, tid = threadIdx.x;
    if (bx < 4096 + 2048) {
        const float* s; unsigned short* d; int i;
        if (bx < 4096) { s = x; d = xb; i = bx * 2048 + tid * 8; }
        else {
            int wb = bx - 4096;
            int wsel = wb >> 9;
            s = wsel == 0 ? qw : (wsel == 1 ? kw : (wsel == 2 ? vw : ow));
            d = wsel == 0 ? wq : (wsel == 1 ? wk : (wsel == 2 ? wv : wo));
            i = (wb & 511) * 2048 + tid * 8;
        }
        float4 a = *(const float4*)(s + i);
        float4 b = *(const float4*)(s + i + 4);
        ushort8 o;
        o[0]=f2bf(a.x); o[1]=f2bf(a.y); o[2]=f2bf(a.z); o[3]=f2bf(a.w);
        o[4]=f2bf(b.x); o[5]=f2bf(b.y); o[6]=f2bf(b.z); o[7]=f2bf(b.w);
        *(ushort8*)(d + i) = o;
    } else if (bx < 6400) {
        int idx = (bx - 6144) * 256 + tid;        // SEQ*32
        int s = idx >> 5, j = idx & 31;
        float t = (float)(2 * j) / 64.0f;
        float freq = 1.0f / powf(10000.0f, t);
        float ang  = (float)s * freq;
        cosT[idx] = cosf(ang);
        sinT[idx] = sinf(ang);
    } else {
        if (tid < 128) {
            int b = tid >> 5, kt = tid & 31;
            const unsigned char* p = mask + b * SEQ + kt * 64;
            unsigned long long v = 0;
            for (int j = 0; j < 64; j++) v |= (unsigned long long)(p[j] != 0) << j;
            m64[tid] = v;
        }
    }
}

// ---------------------------------------------------------------- fused Q,K,V^T GEMM
// blockIdx.x: [0..7]=Q, [8..15]=K (both +RoPE, out [B,H,S,D]), [16..23]=V^T
// (out [B,H,D,S]). Q pre-scaled by 0.125*log2e for exp2-domain softmax.
__global__ __launch_bounds__(256) void gemm_qkvt(const unsigned short* __restrict__ X,
        const unsigned short* __restrict__ Wq, const unsigned short* __restrict__ Wk,
        const unsigned short* __restrict__ Wv,
        const float* __restrict__ bq, const float* __restrict__ bk, const float* __restrict__ bv,
        unsigned short* __restrict__ Qo, unsigned short* __restrict__ Ko, unsigned short* __restrict__ Vto,
        const float* __restrict__ cosT, const float* __restrict__ sinT) {
    __shared__ __align__(16) unsigned short As[128 * 32];
    __shared__ __align__(16) unsigned short Bs[128 * 32];
    const int which = blockIdx.x >> 3;
    const int tid  = threadIdx.x;
    const int wid  = tid >> 6, lane = tid & 63;
    const int quad = lane >> 4, l15 = lane & 15;
    const int wm   = wid >> 1,  wn  = wid & 1;

    const unsigned short *Ag, *Bg;
    int m0, n0;
    if (which < 2) {
        m0 = blockIdx.y * 128;                 // token rows
        n0 = (blockIdx.x & 7) * 128;           // embed cols
        Ag = X;  Bg = which == 0 ? Wq : Wk;
    } else {
        m0 = (blockIdx.x & 7) * 128;           // e rows
        n0 = blockIdx.y * 128;                 // token rows
        Ag = Wv; Bg = X;
    }

    f32x4 acc[4][4];
#pragma unroll
    for (int i = 0; i < 4; i++)
#pragma unroll
        for (int j = 0; j < 4; j++) acc[i][j] = (f32x4)0.0f;

    const int rb = wid * 32 + (lane >> 2);
    const int cb = (lane & 3) * 8;

    for (int k0 = 0; k0 < DIMN; k0 += 32) {
#pragma unroll
        for (int i = 0; i < 2; i++) {
            const unsigned short* ga = Ag + (size_t)(m0 + rb + i * 16) * DIMN + k0 + cb;
            __builtin_amdgcn_global_load_lds((const __attribute__((address_space(1))) void*)ga,
                (__attribute__((address_space(3))) void*)&As[(wid * 32 + i * 16) * 32], 16, 0, 0);
            const unsigned short* gb = Bg + (size_t)(n0 + rb + i * 16) * DIMN + k0 + cb;
            __builtin_amdgcn_global_load_lds((const __attribute__((address_space(1))) void*)gb,
                (__attribute__((address_space(3))) void*)&Bs[(wid * 32 + i * 16) * 32], 16, 0, 0);
        }
        __syncthreads();
        bf16x8 af[4], bfr[4];
#pragma unroll
        for (int f = 0; f < 4; f++) af[f]  = *(const bf16x8*)&As[(wm * 64 + f * 16 + l15) * 32 + quad * 8];
#pragma unroll
        for (int f = 0; f < 4; f++) bfr[f] = *(const bf16x8*)&Bs[(wn * 64 + f * 16 + l15) * 32 + quad * 8];
#pragma unroll
        for (int fm = 0; fm < 4; fm++)
#pragma unroll
            for (int fn = 0; fn < 4; fn++)
                acc[fm][fn] = __builtin_amdgcn_mfma_f32_16x16x32_bf16(af[fm], bfr[fn], acc[fm][fn], 0, 0, 0);
        __syncthreads();
    }

    if (which < 2) {                            // Q or K: +bias, scale, RoPE, [B,H,S,D]
        const float* bias   = which == 0 ? bq : bk;
        unsigned short* Out = which == 0 ? Qo : Ko;
        const float scale = which == 0 ? 0.18033688011112042f : 1.0f;  // 0.125*log2e
        float bv4[4];
#pragma unroll
        for (int fn = 0; fn < 4; fn++) bv4[fn] = bias[n0 + wn * 64 + fn * 16 + l15];
        const int h = (n0 >> 6) + wn;
#pragma unroll
        for (int fm = 0; fm < 4; fm++)
#pragma unroll
            for (int r = 0; r < 4; r++) {
                int mrow = m0 + wm * 64 + fm * 16 + quad * 4 + r;
                int b = mrow >> 11, s = mrow & (SEQ - 1);
                unsigned short* orow = Out + ((size_t)(b * NH + h) * SEQ + s) * HD;
                float v0 = (acc[fm][0][r] + bv4[0]) * scale;
                float v1 = (acc[fm][1][r] + bv4[1]) * scale;
                float v2 = (acc[fm][2][r] + bv4[2]) * scale;
                float v3 = (acc[fm][3][r] + bv4[3]) * scale;
                int d0 = l15, d1 = 16 + l15;
                float c0 = cosT[s * 32 + d0], s0 = sinT[s * 32 + d0];
                float c1 = cosT[s * 32 + d1], s1 = sinT[s * 32 + d1];
                orow[d0]      = f2bf(v0 * c0 - v2 * s0);
                orow[d0 + 32] = f2bf(v0 * s0 + v2 * c0);
                orow[d1]      = f2bf(v1 * c1 - v3 * s1);
                orow[d1 + 32] = f2bf(v1 * s1 + v3 * c1);
            }
    } else {                                    // V^T: [B,H,D,S]
        float4 bb[4];
#pragma unroll
        for (int fm = 0; fm < 4; fm++)
            bb[fm] = *(const float4*)&bv[m0 + wm * 64 + fm * 16 + quad * 4];
        const int b     = n0 >> 11;
        const int sbase = (n0 & (SEQ - 1)) + wn * 64 + l15;
#pragma unroll
        for (int fm = 0; fm < 4; fm++)
#pragma unroll
            for (int r = 0; r < 4; r++) {
                int e = m0 + wm * 64 + fm * 16 + quad * 4 + r;
                float bval = r == 0 ? bb[fm].x : (r == 1 ? bb[fm].y : (r == 2 ? bb[fm].z : bb[fm].w));
                unsigned short* row = Vto + ((size_t)(b * NH + (e >> 6)) * HD + (e & 63)) * SEQ + sbase;
#pragma unroll
                for (int fn = 0; fn < 4; fn++)
                    row[fn * 16] = f2bf(acc[fm][fn][r] + bval);
            }
    }
}

// ---------------------------------------------------------------- output-proj GEMM (fp32 out)
__global__ __launch_bounds__(256) void gemm_bt(const unsigned short* __restrict__ A,
                                               const unsigned short* __restrict__ W,
                                               const float* __restrict__ bias,
                                               float* __restrict__ out) {
    __shared__ __align__(16) unsigned short As[128 * 32];
    __shared__ __align__(16) unsigned short Bs[128 * 32];
    const int tid  = threadIdx.x;
    const int wid  = tid >> 6, lane = tid & 63;
    const int quad = lane >> 4, l15 = lane & 15;
    const int wm   = wid >> 1,  wn  = wid & 1;
    const int m0   = blockIdx.y * 128, n0 = blockIdx.x * 128;

    f32x4 acc[4][4];
#pragma unroll
    for (int i = 0; i < 4; i++)
#pragma unroll
        for (int j = 0; j < 4; j++) acc[i][j] = (f32x4)0.0f;

    const int rb = wid * 32 + (lane >> 2);
    const int cb = (lane & 3) * 8;

    for (int k0 = 0; k0 < DIMN; k0 += 32) {
#pragma unroll
        for (int i = 0; i < 2; i++) {
            const unsigned short* ga = A + (size_t)(m0 + rb + i * 16) * DIMN + k0 + cb;
            __builtin_amdgcn_global_load_lds((const __attribute__((address_space(1))) void*)ga,
                (__attribute__((address_space(3))) void*)&As[(wid * 32 + i * 16) * 32], 16, 0, 0);
            const unsigned short* gb = W + (size_t)(n0 + rb + i * 16) * DIMN + k0 + cb;
            __builtin_amdgcn_global_load_lds((const __attribute__((address_space(1))) void*)gb,
                (__attribute__((address_space(3))) void*)&Bs[(wid * 32 + i * 16) * 32], 16, 0, 0);
        }
        __syncthreads();
        bf16x8 af[4], bfr[4];
#pragma unroll
        for (int f = 0; f < 4; f++) af[f]  = *(const bf16x8*)&As[(wm * 64 + f * 16 + l15) * 32 + quad * 8];
#pragma unroll
        for (int f = 0; f < 4; f++) bfr[f] = *(const bf16x8*)&Bs[(wn * 64 + f * 16 + l15) * 32 + quad * 8];
#pragma unroll
        for (int fm = 0; fm < 4; fm++)
#pragma unroll
            for (int fn = 0; fn < 4; fn++)
                acc[fm][fn] = __builtin_amdgcn_mfma_f32_16x16x32_bf16(af[fm], bfr[fn], acc[fm][fn], 0, 0, 0);
        __syncthreads();
    }

    float bv4[4];
#pragma unroll
    for (int fn = 0; fn < 4; fn++) bv4[fn] = bias[n0 + wn * 64 + fn * 16 + l15];
#pragma unroll
    for (int fm = 0; fm < 4; fm++)
#pragma unroll
        for (int r = 0; r < 4; r++) {
            int mrow = m0 + wm * 64 + fm * 16 + quad * 4 + r;
            float* orow = out + (size_t)mrow * DIMN + n0 + wn * 64;
#pragma unroll
            for (int fn = 0; fn < 4; fn++) orow[fn * 16 + l15] = acc[fm][fn][r] + bv4[fn];
        }
}

// ---------------------------------------------------------------- flash attention v7
// grid (SEQ/128, B*NH), 4 waves x 32 q-rows. K/V staged to LDS via
// global_load_lds (no VGPR round-trip -> no spill) into a FRAGMENT CACHE:
// slab s (1 KiB) holds one MFMA operand fragment in exact lane order
// (base + lane*16B), which is both the DMA's required dest layout and a
// linear conflict-minimal ds_read_b128. Wave w stages 2 K-slabs + 2 V-slabs;
// all waves consume all 16 slabs (4x traffic reduction vs direct-global).
// Halved-kk wave-private P round-trip. No online max (exp2, Q pre-scaled).
__global__ __launch_bounds__(256, 4) void attn_kernel(const unsigned short* __restrict__ Q,
                                                      const unsigned short* __restrict__ K,
                                                      const unsigned short* __restrict__ Vt,
                                                      const unsigned long long* __restrict__ M64,
                                                      unsigned short* __restrict__ Ob) {
    __shared__ __align__(16) unsigned short Ks[8 * 512];       //  8 KiB: slab f*2+dk
    __shared__ __align__(16) unsigned short Vs[8 * 512];       //  8 KiB: slab df*2+h2
    __shared__ __align__(16) unsigned short Ps[4 * 32 * 40];   // 10 KiB wave-private

    const int tid  = threadIdx.x;
    const int wid  = tid >> 6, lane = tid & 63;
    const int quad = lane >> 4, l15 = lane & 15;
    const int bh = blockIdx.y, b = bh >> 4, h = bh & 15;
    const int q0 = blockIdx.x * 128;

    // persistent Q fragments: q = q0 + wid*32 + n*16 + l15
    bf16x8 qf[2][2];
#pragma unroll
    for (int n = 0; n < 2; n++) {
        const int qs = q0 + wid * 32 + n * 16 + l15;
#pragma unroll
        for (int dk = 0; dk < 2; dk++)
            qf[n][dk] = __builtin_bit_cast(bf16x8,
                *(const uint4*)&Q[((size_t)bh * SEQ + qs) * HD + dk * 32 + quad * 8]);
    }

    f32x4 Oa[4][2];                      // O^T: [df][n]; lane: d=df*16+quad*4+r, q=n*16+l15
#pragma unroll
    for (int i = 0; i < 4; i++)
#pragma unroll
        for (int n = 0; n < 2; n++) Oa[i][n] = (f32x4)0.0f;
    float ls[2] = {0.0f, 0.0f};

    unsigned short* Pw = &Ps[wid * 32 * 40];
    const unsigned long long* Mrow = M64 + b * (SEQ / 64);

    // this wave's staging slabs: s0 = wid*2, s1 = wid*2+1 (applies to K and V)
    const int s0 = wid * 2, s1 = s0 + 1;
    const unsigned short* Kg = K + (size_t)bh * SEQ * HD;
    const unsigned short* Vg = Vt + (size_t)bh * HD * SEQ;
    // K slab s: row = k0 + (s>>1)*16 + l15, col = (s&1)*32 + quad*8
    const unsigned short* gk0 = Kg + (size_t)((s0 >> 1) * 16 + l15) * HD + (s0 & 1) * 32 + quad * 8;
    const unsigned short* gk1 = Kg + (size_t)((s1 >> 1) * 16 + l15) * HD + (s1 & 1) * 32 + quad * 8;
    // V slab s: row = (s>>1)*16 + l15 (d), col = k0 + (s&1)*32 + quad*8 (seq)
    const unsigned short* gv0 = Vg + (size_t)((s0 >> 1) * 16 + l15) * SEQ + (s0 & 1) * 32 + quad * 8;
    const unsigned short* gv1 = Vg + (size_t)((s1 >> 1) * 16 + l15) * SEQ + (s1 & 1) * 32 + quad * 8;

    for (int kt = 0; kt < SEQ / 64; kt++) {
        const int k0 = kt * 64;
        __builtin_amdgcn_global_load_lds(
            (const __attribute__((address_space(1))) void*)(gk0 + (size_t)k0 * HD),
            (__attribute__((address_space(3))) void*)&Ks[s0 * 512], 16, 0, 0);
        __builtin_amdgcn_global_load_lds(
            (const __attribute__((address_space(1))) void*)(gk1 + (size_t)k0 * HD),
            (__attribute__((address_space(3))) void*)&Ks[s1 * 512], 16, 0, 0);
        __builtin_amdgcn_global_load_lds(
            (const __attribute__((address_space(1))) void*)(gv0 + k0),
            (__attribute__((address_space(3))) void*)&Vs[s0 * 512], 16, 0, 0);
        __builtin_amdgcn_global_load_lds(
            (const __attribute__((address_space(1))) void*)(gv1 + k0),
            (__attribute__((address_space(3))) void*)&Vs[s1 * 512], 16, 0, 0);
        unsigned long long mb = Mrow[kt];
        __syncthreads();                 // drains vmcnt: slabs visible to all waves

#pragma unroll
        for (int h2 = 0; h2 < 2; h2++) {      // 32-kk half
            bf16x8 kf[2][2];
#pragma unroll
            for (int f2 = 0; f2 < 2; f2++)
#pragma unroll
                for (int dk = 0; dk < 2; dk++)
                    kf[f2][dk] = *(const bf16x8*)&Ks[(((h2 * 2 + f2) << 1) + dk) * 512 + lane * 8];
            bf16x8 vf[4];
#pragma unroll
            for (int df = 0; df < 4; df++)
                vf[df] = *(const bf16x8*)&Vs[((df << 1) + h2) * 512 + lane * 8];

            f32x4 st[2][2];
#pragma unroll
            for (int f2 = 0; f2 < 2; f2++)
#pragma unroll
                for (int n = 0; n < 2; n++) {
                    st[f2][n] = __builtin_amdgcn_mfma_f32_16x16x32_bf16(kf[f2][0], qf[n][0], (f32x4)0.0f, 0, 0, 0);
                    st[f2][n] = __builtin_amdgcn_mfma_f32_16x16x32_bf16(kf[f2][1], qf[n][1], st[f2][n], 0, 0, 0);
                }

            unsigned int mh = (unsigned int)(mb >> (h2 * 32));
            if (mh) {                         // wave-uniform; rare
#pragma unroll
                for (int f2 = 0; f2 < 2; f2++)
#pragma unroll
                    for (int n = 0; n < 2; n++)
#pragma unroll
                        for (int r = 0; r < 4; r++) {
                            int kk = f2 * 16 + quad * 4 + r;
                            if ((mh >> kk) & 1u) st[f2][n][r] = -1e9f;
                        }
            }

            // exp2, sum, pack, wave-private P^T half round-trip (no barrier)
#pragma unroll
            for (int f2 = 0; f2 < 2; f2++)
#pragma unroll
                for (int n = 0; n < 2; n++) {
                    float p0 = exp2f(st[f2][n][0]);
                    float p1 = exp2f(st[f2][n][1]);
                    float p2 = exp2f(st[f2][n][2]);
                    float p3 = exp2f(st[f2][n][3]);
                    ls[n] += (p0 + p1) + (p2 + p3);
                    uint2 w;
                    w.x = pack2bf_trunc(p0, p1);
                    w.y = pack2bf_trunc(p2, p3);
                    *(uint2*)&Pw[(n * 16 + l15) * 40 + f2 * 16 + quad * 4] = w;
                }
            bf16x8 pf[2];
#pragma unroll
            for (int n = 0; n < 2; n++)
                pf[n] = *(const bf16x8*)&Pw[(n * 16 + l15) * 40 + quad * 8];
#pragma unroll
            for (int df = 0; df < 4; df++)
#pragma unroll
                for (int n = 0; n < 2; n++)
                    Oa[df][n] = __builtin_amdgcn_mfma_f32_16x16x32_bf16(vf[df], pf[n], Oa[df][n], 0, 0, 0);
        }
        __syncthreads();                 // before next tile overwrites slabs
    }

    float linv[2];
#pragma unroll
    for (int n = 0; n < 2; n++) {
        float l = ls[n];
        l += __shfl_xor(l, 16);
        l += __shfl_xor(l, 32);
        linv[n] = 1.0f / l;
    }

#pragma unroll
    for (int n = 0; n < 2; n++) {
        int s = q0 + wid * 32 + n * 16 + l15;
        unsigned short* orow = Ob + ((size_t)b * SEQ + s) * DIMN + h * HD + quad * 4;
#pragma unroll
        for (int df = 0; df < 4; df++) {
            uint2 w;
            w.x = pack2bf(Oa[df][n][0] * linv[n], Oa[df][n][1] * linv[n]);
            w.y = pack2bf(Oa[df][n][2] * linv[n], Oa[df][n][3] * linv[n]);
            *(uint2*)&orow[df * 16] = w;
        }
    }
}

// ---------------------------------------------------------------- launch
extern "C" void kernel_launch(void* const* d_in, const int* in_sizes, int n_in,
                              void* d_out, int out_size, void* d_ws, size_t ws_size,
                              hipStream_t stream) {
    (void)in_sizes; (void)n_in; (void)out_size; (void)ws_size;
    const float* x  = (const float*)d_in[0];
    const unsigned char* mask = (const unsigned char*)d_in[1];
    const float* q_w = (const float*)d_in[2];
    const float* q_b = (const float*)d_in[3];
    const float* k_w = (const float*)d_in[4];
    const float* k_b = (const float*)d_in[5];
    const float* v_w = (const float*)d_in[6];
    const float* v_b = (const float*)d_in[7];
    const float* o_w = (const float*)d_in[8];
    const float* o_b = (const float*)d_in[9];
    float* out = (float*)d_out;

    char* w = (char*)d_ws;
    unsigned short* xb = (unsigned short*)w;                        // 16 MiB (reused as attn output)
    unsigned short* wq = (unsigned short*)(w + (16u << 20));        // 4 x 2 MiB
    unsigned short* wk = wq + (1u << 20);
    unsigned short* wv = wk + (1u << 20);
    unsigned short* wo = wv + (1u << 20);
    float* cosT = (float*)(w + (24u << 20));                        // 256 KiB
    float* sinT = cosT + SEQ * 32;
    unsigned long long* m64 = (unsigned long long*)(w + (24u << 20) + (1u << 19)); // 1 KiB
    unsigned short* Qb  = (unsigned short*)(w + (25u << 20));       // 3 x 16 MiB
    unsigned short* Kb  = Qb + (8u << 20);
    unsigned short* Vtb = Kb + (8u << 20);
    unsigned short* Ob  = xb;                                       // reuse x's slot

    prologue_kernel<<<dim3(6401), 256, 0, stream>>>(x, q_w, k_w, v_w, o_w,
                                                    xb, wq, wk, wv, wo,
                                                    cosT, sinT, mask, m64);

    gemm_qkvt<<<dim3(24, 64), 256, 0, stream>>>(xb, wq, wk, wv, q_b, k_b, v_b,
                                                Qb, Kb, Vtb, cosT, sinT);

    attn_kernel<<<dim3(SEQ / 128, BATCH * NH), 256, 0, stream>>>(Qb, Kb, Vtb, m64, Ob);

    gemm_bt<<<dim3(DIMN / 128, MROWS / 128), 256, 0, stream>>>(Ob, wo, o_b, out);
}

// Round 8
// 289.812 us; speedup vs baseline: 1.5096x; 1.1082x over previous
//
#include <hip/hip_runtime.h>
#include <stdint.h>

#define SEQ   2048
#define BATCH 4
#define NH    16
#define HD    64
#define DIMN  1024
#define MROWS (BATCH*SEQ)   // 8192

typedef __attribute__((ext_vector_type(8))) short          bf16x8;
typedef __attribute__((ext_vector_type(8))) unsigned short ushort8;
typedef __attribute__((ext_vector_type(4))) float          f32x4;

static __device__ __forceinline__ unsigned short f2bf(float f) {
    unsigned int u = __builtin_bit_cast(unsigned int, f);
    u += 0x7fffu + ((u >> 16) & 1u);          // RNE
    return (unsigned short)(u >> 16);
}
// RNE-ish (round-half-up) pack: 3 ops
static __device__ __forceinline__ unsigned int pack2bf(float lo, float hi) {
    unsigned int a = __builtin_bit_cast(unsigned int, lo) + 0x8000u;
    unsigned int b = __builtin_bit_cast(unsigned int, hi) + 0x8000u;
    return __builtin_amdgcn_perm(b, a, 0x07060302u);
}
// truncating pack: 1 op (P in [0,1], rel err <= 2^-8, fine for softmax weights)
static __device__ __forceinline__ unsigned int pack2bf_trunc(float lo, float hi) {
    return __builtin_amdgcn_perm(__builtin_bit_cast(unsigned int, hi),
                                 __builtin_bit_cast(unsigned int, lo), 0x07060302u);
}

// ---------------------------------------------------------------- fused prologue
// blockIdx.x: [0,4096) x-cast; [4096,6144) 4 weight casts; [6144,6400) rope
// tables; 6400 mask->u64. All branches wave-uniform.
__global__ __launch_bounds__(256) void prologue_kernel(
        const float* __restrict__ x,
        const float* __restrict__ qw, const float* __restrict__ kw,
        const float* __restrict__ vw, const float* __restrict__ ow,
        unsigned short* __restrict__ xb,
        unsigned short* __restrict__ wq, unsigned short* __restrict__ wk,
        unsigned short* __restrict__ wv, unsigned short* __restrict__ wo,
        float* __restrict__ cosT, float* __restrict__ sinT,
        const unsigned char* __restrict__ mask, unsigned long long* __restrict__ m64) {
    const int bx = blockIdx.x, tid = threadIdx.x;
    if (bx < 4096 + 2048) {
        const float* s; unsigned short* d; int i;
        if (bx < 4096) { s = x; d = xb; i = bx * 2048 + tid * 8; }
        else {
            int wb = bx - 4096;
            int wsel = wb >> 9;
            s = wsel == 0 ? qw : (wsel == 1 ? kw : (wsel == 2 ? vw : ow));
            d = wsel == 0 ? wq : (wsel == 1 ? wk : (wsel == 2 ? wv : wo));
            i = (wb & 511) * 2048 + tid * 8;
        }
        float4 a = *(const float4*)(s + i);
        float4 b = *(const float4*)(s + i + 4);
        ushort8 o;
        o[0]=f2bf(a.x); o[1]=f2bf(a.y); o[2]=f2bf(a.z); o[3]=f2bf(a.w);
        o[4]=f2bf(b.x); o[5]=f2bf(b.y); o[6]=f2bf(b.z); o[7]=f2bf(b.w);
        *(ushort8*)(d + i) = o;
    } else if (bx < 6400) {
        int idx = (bx - 6144) * 256 + tid;        // SEQ*32
        int s = idx >> 5, j = idx & 31;
        float t = (float)(2 * j) / 64.0f;
        float freq = 1.0f / powf(10000.0f, t);
        float ang  = (float)s * freq;
        cosT[idx] = cosf(ang);
        sinT[idx] = sinf(ang);
    } else {
        if (tid < 128) {
            int b = tid >> 5, kt = tid & 31;
            const unsigned char* p = mask + b * SEQ + kt * 64;
            unsigned long long v = 0;
            for (int j = 0; j < 64; j++) v |= (unsigned long long)(p[j] != 0) << j;
            m64[tid] = v;
        }
    }
}

// ---------------------------------------------------------------- fused Q,K,V^T GEMM
// blockIdx.x: [0..7]=Q, [8..15]=K (both +RoPE, out [B,H,S,D]), [16..23]=V^T
// (out [B,H,D,S]). Q pre-scaled by 0.125*log2e for exp2-domain softmax.
__global__ __launch_bounds__(256) void gemm_qkvt(const unsigned short* __restrict__ X,
        const unsigned short* __restrict__ Wq, const unsigned short* __restrict__ Wk,
        const unsigned short* __restrict__ Wv,
        const float* __restrict__ bq, const float* __restrict__ bk, const float* __restrict__ bv,
        unsigned short* __restrict__ Qo, unsigned short* __restrict__ Ko, unsigned short* __restrict__ Vto,
        const float* __restrict__ cosT, const float* __restrict__ sinT) {
    __shared__ __align__(16) unsigned short As[128 * 32];
    __shared__ __align__(16) unsigned short Bs[128 * 32];
    const int which = blockIdx.x >> 3;
    const int tid  = threadIdx.x;
    const int wid  = tid >> 6, lane = tid & 63;
    const int quad = lane >> 4, l15 = lane & 15;
    const int wm   = wid >> 1,  wn  = wid & 1;

    const unsigned short *Ag, *Bg;
    int m0, n0;
    if (which < 2) {
        m0 = blockIdx.y * 128;                 // token rows
        n0 = (blockIdx.x & 7) * 128;           // embed cols
        Ag = X;  Bg = which == 0 ? Wq : Wk;
    } else {
        m0 = (blockIdx.x & 7) * 128;           // e rows
        n0 = blockIdx.y * 128;                 // token rows
        Ag = Wv; Bg = X;
    }

    f32x4 acc[4][4];
#pragma unroll
    for (int i = 0; i < 4; i++)
#pragma unroll
        for (int j = 0; j < 4; j++) acc[i][j] = (f32x4)0.0f;

    const int rb = wid * 32 + (lane >> 2);
    const int cb = (lane & 3) * 8;

    for (int k0 = 0; k0 < DIMN; k0 += 32) {
#pragma unroll
        for (int i = 0; i < 2; i++) {
            const unsigned short* ga = Ag + (size_t)(m0 + rb + i * 16) * DIMN + k0 + cb;
            __builtin_amdgcn_global_load_lds((const __attribute__((address_space(1))) void*)ga,
                (__attribute__((address_space(3))) void*)&As[(wid * 32 + i * 16) * 32], 16, 0, 0);
            const unsigned short* gb = Bg + (size_t)(n0 + rb + i * 16) * DIMN + k0 + cb;
            __builtin_amdgcn_global_load_lds((const __attribute__((address_space(1))) void*)gb,
                (__attribute__((address_space(3))) void*)&Bs[(wid * 32 + i * 16) * 32], 16, 0, 0);
        }
        __syncthreads();
        bf16x8 af[4], bfr[4];
#pragma unroll
        for (int f = 0; f < 4; f++) af[f]  = *(const bf16x8*)&As[(wm * 64 + f * 16 + l15) * 32 + quad * 8];
#pragma unroll
        for (int f = 0; f < 4; f++) bfr[f] = *(const bf16x8*)&Bs[(wn * 64 + f * 16 + l15) * 32 + quad * 8];
#pragma unroll
        for (int fm = 0; fm < 4; fm++)
#pragma unroll
            for (int fn = 0; fn < 4; fn++)
                acc[fm][fn] = __builtin_amdgcn_mfma_f32_16x16x32_bf16(af[fm], bfr[fn], acc[fm][fn], 0, 0, 0);
        __syncthreads();
    }

    if (which < 2) {                            // Q or K: +bias, scale, RoPE, [B,H,S,D]
        const float* bias   = which == 0 ? bq : bk;
        unsigned short* Out = which == 0 ? Qo : Ko;
        const float scale = which == 0 ? 0.18033688011112042f : 1.0f;  // 0.125*log2e
        float bv4[4];
#pragma unroll
        for (int fn = 0; fn < 4; fn++) bv4[fn] = bias[n0 + wn * 64 + fn * 16 + l15];
        const int h = (n0 >> 6) + wn;
#pragma unroll
        for (int fm = 0; fm < 4; fm++)
#pragma unroll
            for (int r = 0; r < 4; r++) {
                int mrow = m0 + wm * 64 + fm * 16 + quad * 4 + r;
                int b = mrow >> 11, s = mrow & (SEQ - 1);
                unsigned short* orow = Out + ((size_t)(b * NH + h) * SEQ + s) * HD;
                float v0 = (acc[fm][0][r] + bv4[0]) * scale;
                float v1 = (acc[fm][1][r] + bv4[1]) * scale;
                float v2 = (acc[fm][2][r] + bv4[2]) * scale;
                float v3 = (acc[fm][3][r] + bv4[3]) * scale;
                int d0 = l15, d1 = 16 + l15;
                float c0 = cosT[s * 32 + d0], s0 = sinT[s * 32 + d0];
                float c1 = cosT[s * 32 + d1], s1 = sinT[s * 32 + d1];
                orow[d0]      = f2bf(v0 * c0 - v2 * s0);
                orow[d0 + 32] = f2bf(v0 * s0 + v2 * c0);
                orow[d1]      = f2bf(v1 * c1 - v3 * s1);
                orow[d1 + 32] = f2bf(v1 * s1 + v3 * c1);
            }
    } else {                                    // V^T: [B,H,D,S]
        float4 bb[4];
#pragma unroll
        for (int fm = 0; fm < 4; fm++)
            bb[fm] = *(const float4*)&bv[m0 + wm * 64 + fm * 16 + quad * 4];
        const int b     = n0 >> 11;
        const int sbase = (n0 & (SEQ - 1)) + wn * 64 + l15;
#pragma unroll
        for (int fm = 0; fm < 4; fm++)
#pragma unroll
            for (int r = 0; r < 4; r++) {
                int e = m0 + wm * 64 + fm * 16 + quad * 4 + r;
                float bval = r == 0 ? bb[fm].x : (r == 1 ? bb[fm].y : (r == 2 ? bb[fm].z : bb[fm].w));
                unsigned short* row = Vto + ((size_t)(b * NH + (e >> 6)) * HD + (e & 63)) * SEQ + sbase;
#pragma unroll
                for (int fn = 0; fn < 4; fn++)
                    row[fn * 16] = f2bf(acc[fm][fn][r] + bval);
            }
    }
}

// ---------------------------------------------------------------- output-proj GEMM (fp32 out)
__global__ __launch_bounds__(256) void gemm_bt(const unsigned short* __restrict__ A,
                                               const unsigned short* __restrict__ W,
                                               const float* __restrict__ bias,
                                               float* __restrict__ out) {
    __shared__ __align__(16) unsigned short As[128 * 32];
    __shared__ __align__(16) unsigned short Bs[128 * 32];
    const int tid  = threadIdx.x;
    const int wid  = tid >> 6, lane = tid & 63;
    const int quad = lane >> 4, l15 = lane & 15;
    const int wm   = wid >> 1,  wn  = wid & 1;
    const int m0   = blockIdx.y * 128, n0 = blockIdx.x * 128;

    f32x4 acc[4][4];
#pragma unroll
    for (int i = 0; i < 4; i++)
#pragma unroll
        for (int j = 0; j < 4; j++) acc[i][j] = (f32x4)0.0f;

    const int rb = wid * 32 + (lane >> 2);
    const int cb = (lane & 3) * 8;

    for (int k0 = 0; k0 < DIMN; k0 += 32) {
#pragma unroll
        for (int i = 0; i < 2; i++) {
            const unsigned short* ga = A + (size_t)(m0 + rb + i * 16) * DIMN + k0 + cb;
            __builtin_amdgcn_global_load_lds((const __attribute__((address_space(1))) void*)ga,
                (__attribute__((address_space(3))) void*)&As[(wid * 32 + i * 16) * 32], 16, 0, 0);
            const unsigned short* gb = W + (size_t)(n0 + rb + i * 16) * DIMN + k0 + cb;
            __builtin_amdgcn_global_load_lds((const __attribute__((address_space(1))) void*)gb,
                (__attribute__((address_space(3))) void*)&Bs[(wid * 32 + i * 16) * 32], 16, 0, 0);
        }
        __syncthreads();
        bf16x8 af[4], bfr[4];
#pragma unroll
        for (int f = 0; f < 4; f++) af[f]  = *(const bf16x8*)&As[(wm * 64 + f * 16 + l15) * 32 + quad * 8];
#pragma unroll
        for (int f = 0; f < 4; f++) bfr[f] = *(const bf16x8*)&Bs[(wn * 64 + f * 16 + l15) * 32 + quad * 8];
#pragma unroll
        for (int fm = 0; fm < 4; fm++)
#pragma unroll
            for (int fn = 0; fn < 4; fn++)
                acc[fm][fn] = __builtin_amdgcn_mfma_f32_16x16x32_bf16(af[fm], bfr[fn], acc[fm][fn], 0, 0, 0);
        __syncthreads();
    }

    float bv4[4];
#pragma unroll
    for (int fn = 0; fn < 4; fn++) bv4[fn] = bias[n0 + wn * 64 + fn * 16 + l15];
#pragma unroll
    for (int fm = 0; fm < 4; fm++)
#pragma unroll
        for (int r = 0; r < 4; r++) {
            int mrow = m0 + wm * 64 + fm * 16 + quad * 4 + r;
            float* orow = out + (size_t)mrow * DIMN + n0 + wn * 64;
#pragma unroll
            for (int fn = 0; fn < 4; fn++) orow[fn * 16 + l15] = acc[fm][fn][r] + bv4[fn];
        }
}

// ---------------------------------------------------------------- flash attention v8
// 1D grid 1024, XCD-swizzled: all 16 q-blocks of a (b,h) land on one XCD so
// its private L2 fetches K/V once. 4 waves x 32 q-rows. K/V staged via
// global_load_lds fragment-cache slabs (lane-ordered, no VGPR round-trip).
// Raw v_exp_f32 via __builtin_amdgcn_exp2f (OCML denorm path was the VALU
// hog). Halved-kk wave-private P round-trip. No online max (exp2 domain,
// Q pre-scaled by 0.125*log2e).
__global__ __launch_bounds__(256, 4) void attn_kernel(const unsigned short* __restrict__ Q,
                                                      const unsigned short* __restrict__ K,
                                                      const unsigned short* __restrict__ Vt,
                                                      const unsigned long long* __restrict__ M64,
                                                      unsigned short* __restrict__ Ob) {
    __shared__ __align__(16) unsigned short Ks[8 * 512];       //  8 KiB: slab f*2+dk
    __shared__ __align__(16) unsigned short Vs[8 * 512];       //  8 KiB: slab df*2+h2
    __shared__ __align__(16) unsigned short Ps[4 * 32 * 40];   // 10 KiB wave-private

    const int tid  = threadIdx.x;
    const int wid  = tid >> 6, lane = tid & 63;
    const int quad = lane >> 4, l15 = lane & 15;
    // XCD-aware swizzle: xcd = bid&7 (round-robin dispatch heuristic);
    // each XCD owns 8 complete (b,h) groups -> K/V L2-resident per XCD.
    const int bid = blockIdx.x;
    const int bh  = (bid & 7) * 8 + (bid >> 7);
    const int qt  = (bid >> 3) & 15;
    const int b = bh >> 4, h = bh & 15;
    const int q0 = qt * 128;

    // persistent Q fragments: q = q0 + wid*32 + n*16 + l15
    bf16x8 qf[2][2];
#pragma unroll
    for (int n = 0; n < 2; n++) {
        const int qs = q0 + wid * 32 + n * 16 + l15;
#pragma unroll
        for (int dk = 0; dk < 2; dk++)
            qf[n][dk] = __builtin_bit_cast(bf16x8,
                *(const uint4*)&Q[((size_t)bh * SEQ + qs) * HD + dk * 32 + quad * 8]);
    }

    f32x4 Oa[4][2];                      // O^T: [df][n]; lane: d=df*16+quad*4+r, q=n*16+l15
#pragma unroll
    for (int i = 0; i < 4; i++)
#pragma unroll
        for (int n = 0; n < 2; n++) Oa[i][n] = (f32x4)0.0f;
    float ls[2] = {0.0f, 0.0f};

    unsigned short* Pw = &Ps[wid * 32 * 40];
    const unsigned long long* Mrow = M64 + b * (SEQ / 64);

    // this wave's staging slabs: s0 = wid*2, s1 = wid*2+1 (applies to K and V)
    const int s0 = wid * 2, s1 = s0 + 1;
    const unsigned short* Kg = K + (size_t)bh * SEQ * HD;
    const unsigned short* Vg = Vt + (size_t)bh * HD * SEQ;
    // K slab s: row = k0 + (s>>1)*16 + l15, col = (s&1)*32 + quad*8
    const unsigned short* gk0 = Kg + (size_t)((s0 >> 1) * 16 + l15) * HD + (s0 & 1) * 32 + quad * 8;
    const unsigned short* gk1 = Kg + (size_t)((s1 >> 1) * 16 + l15) * HD + (s1 & 1) * 32 + quad * 8;
    // V slab s: row = (s>>1)*16 + l15 (d), col = k0 + (s&1)*32 + quad*8 (seq)
    const unsigned short* gv0 = Vg + (size_t)((s0 >> 1) * 16 + l15) * SEQ + (s0 & 1) * 32 + quad * 8;
    const unsigned short* gv1 = Vg + (size_t)((s1 >> 1) * 16 + l15) * SEQ + (s1 & 1) * 32 + quad * 8;

    for (int kt = 0; kt < SEQ / 64; kt++) {
        const int k0 = kt * 64;
        __builtin_amdgcn_global_load_lds(
            (const __attribute__((address_space(1))) void*)(gk0 + (size_t)k0 * HD),
            (__attribute__((address_space(3))) void*)&Ks[s0 * 512], 16, 0, 0);
        __builtin_amdgcn_global_load_lds(
            (const __attribute__((address_space(1))) void*)(gk1 + (size_t)k0 * HD),
            (__attribute__((address_space(3))) void*)&Ks[s1 * 512], 16, 0, 0);
        __builtin_amdgcn_global_load_lds(
            (const __attribute__((address_space(1))) void*)(gv0 + k0),
            (__attribute__((address_space(3))) void*)&Vs[s0 * 512], 16, 0, 0);
        __builtin_amdgcn_global_load_lds(
            (const __attribute__((address_space(1))) void*)(gv1 + k0),
            (__attribute__((address_space(3))) void*)&Vs[s1 * 512], 16, 0, 0);
        unsigned long long mb = Mrow[kt];
        __syncthreads();                 // drains vmcnt: slabs visible to all waves

#pragma unroll
        for (int h2 = 0; h2 < 2; h2++) {      // 32-kk half
            bf16x8 kf[2][2];
#pragma unroll
            for (int f2 = 0; f2 < 2; f2++)
#pragma unroll
                for (int dk = 0; dk < 2; dk++)
                    kf[f2][dk] = *(const bf16x8*)&Ks[(((h2 * 2 + f2) << 1) + dk) * 512 + lane * 8];
            bf16x8 vf[4];
#pragma unroll
            for (int df = 0; df < 4; df++)
                vf[df] = *(const bf16x8*)&Vs[((df << 1) + h2) * 512 + lane * 8];

            f32x4 st[2][2];
#pragma unroll
            for (int f2 = 0; f2 < 2; f2++)
#pragma unroll
                for (int n = 0; n < 2; n++) {
                    st[f2][n] = __builtin_amdgcn_mfma_f32_16x16x32_bf16(kf[f2][0], qf[n][0], (f32x4)0.0f, 0, 0, 0);
                    st[f2][n] = __builtin_amdgcn_mfma_f32_16x16x32_bf16(kf[f2][1], qf[n][1], st[f2][n], 0, 0, 0);
                }

            unsigned int mh = (unsigned int)(mb >> (h2 * 32));
            if (mh) {                         // wave-uniform; rare
#pragma unroll
                for (int f2 = 0; f2 < 2; f2++)
#pragma unroll
                    for (int n = 0; n < 2; n++)
#pragma unroll
                        for (int r = 0; r < 4; r++) {
                            int kk = f2 * 16 + quad * 4 + r;
                            if ((mh >> kk) & 1u) st[f2][n][r] = -1e9f;
                        }
            }

            // raw v_exp_f32, sum, pack, wave-private P^T half round-trip
#pragma unroll
            for (int f2 = 0; f2 < 2; f2++)
#pragma unroll
                for (int n = 0; n < 2; n++) {
                    float p0 = __builtin_amdgcn_exp2f(st[f2][n][0]);
                    float p1 = __builtin_amdgcn_exp2f(st[f2][n][1]);
                    float p2 = __builtin_amdgcn_exp2f(st[f2][n][2]);
                    float p3 = __builtin_amdgcn_exp2f(st[f2][n][3]);
                    ls[n] += (p0 + p1) + (p2 + p3);
                    uint2 w;
                    w.x = pack2bf_trunc(p0, p1);
                    w.y = pack2bf_trunc(p2, p3);
                    *(uint2*)&Pw[(n * 16 + l15) * 40 + f2 * 16 + quad * 4] = w;
                }
            bf16x8 pf[2];
#pragma unroll
            for (int n = 0; n < 2; n++)
                pf[n] = *(const bf16x8*)&Pw[(n * 16 + l15) * 40 + quad * 8];
#pragma unroll
            for (int df = 0; df < 4; df++)
#pragma unroll
                for (int n = 0; n < 2; n++)
                    Oa[df][n] = __builtin_amdgcn_mfma_f32_16x16x32_bf16(vf[df], pf[n], Oa[df][n], 0, 0, 0);
        }
        __syncthreads();                 // before next tile overwrites slabs
    }

    float linv[2];
#pragma unroll
    for (int n = 0; n < 2; n++) {
        float l = ls[n];
        l += __shfl_xor(l, 16);
        l += __shfl_xor(l, 32);
        linv[n] = 1.0f / l;
    }

#pragma unroll
    for (int n = 0; n < 2; n++) {
        int s = q0 + wid * 32 + n * 16 + l15;
        unsigned short* orow = Ob + ((size_t)b * SEQ + s) * DIMN + h * HD + quad * 4;
#pragma unroll
        for (int df = 0; df < 4; df++) {
            uint2 w;
            w.x = pack2bf(Oa[df][n][0] * linv[n], Oa[df][n][1] * linv[n]);
            w.y = pack2bf(Oa[df][n][2] * linv[n], Oa[df][n][3] * linv[n]);
            *(uint2*)&orow[df * 16] = w;
        }
    }
}

// ---------------------------------------------------------------- launch
extern "C" void kernel_launch(void* const* d_in, const int* in_sizes, int n_in,
                              void* d_out, int out_size, void* d_ws, size_t ws_size,
                              hipStream_t stream) {
    (void)in_sizes; (void)n_in; (void)out_size; (void)ws_size;
    const float* x  = (const float*)d_in[0];
    const unsigned char* mask = (const unsigned char*)d_in[1];
    const float* q_w = (const float*)d_in[2];
    const float* q_b = (const float*)d_in[3];
    const float* k_w = (const float*)d_in[4];
    const float* k_b = (const float*)d_in[5];
    const float* v_w = (const float*)d_in[6];
    const float* v_b = (const float*)d_in[7];
    const float* o_w = (const float*)d_in[8];
    const float* o_b = (const float*)d_in[9];
    float* out = (float*)d_out;

    char* w = (char*)d_ws;
    unsigned short* xb = (unsigned short*)w;                        // 16 MiB (reused as attn output)
    unsigned short* wq = (unsigned short*)(w + (16u << 20));        // 4 x 2 MiB
    unsigned short* wk = wq + (1u << 20);
    unsigned short* wv = wk + (1u << 20);
    unsigned short* wo = wv + (1u << 20);
    float* cosT = (float*)(w + (24u << 20));                        // 256 KiB
    float* sinT = cosT + SEQ * 32;
    unsigned long long* m64 = (unsigned long long*)(w + (24u << 20) + (1u << 19)); // 1 KiB
    unsigned short* Qb  = (unsigned short*)(w + (25u << 20));       // 3 x 16 MiB
    unsigned short* Kb  = Qb + (8u << 20);
    unsigned short* Vtb = Kb + (8u << 20);
    unsigned short* Ob  = xb;                                       // reuse x's slot

    prologue_kernel<<<dim3(6401), 256, 0, stream>>>(x, q_w, k_w, v_w, o_w,
                                                    xb, wq, wk, wv, wo,
                                                    cosT, sinT, mask, m64);

    gemm_qkvt<<<dim3(24, 64), 256, 0, stream>>>(xb, wq, wk, wv, q_b, k_b, v_b,
                                                Qb, Kb, Vtb, cosT, sinT);

    attn_kernel<<<dim3(1024), 256, 0, stream>>>(Qb, Kb, Vtb, m64, Ob);

    gemm_bt<<<dim3(DIMN / 128, MROWS / 128), 256, 0, stream>>>(Ob, wo, o_b, out);
}